// Round 2
// baseline (1145.554 us; speedup 1.0000x reference)
//
#include <hip/hip_runtime.h>
#include <hip/hip_bf16.h>
#include <cstdint>
#include <cstddef>

typedef __hip_bfloat16 BF;
typedef __attribute__((ext_vector_type(8))) short bhalf8;   // 8 bf16 = 4 VGPRs (MFMA A/B frag)
typedef __attribute__((ext_vector_type(4))) float floatx4;  // MFMA C/D frag

// Problem constants
#define NB 8
#define NC 512
#define NHW 4096
#define NG 32

__device__ __forceinline__ float b2f(short h) {
    union { unsigned u; float f; } c;
    c.u = ((unsigned)(unsigned short)h) << 16;
    return c.f;
}
__device__ __forceinline__ short f2b(float f) {
    __hip_bfloat16 h = __float2bfloat16(f);
    short s;
    __builtin_memcpy(&s, &h, 2);
    return s;
}

// ---------------------------------------------------------------------------
// Convert fp32 -> bf16 (weights). n elems, each thread does 4.
// ---------------------------------------------------------------------------
__global__ __launch_bounds__(256) void f2b_convert(const float* __restrict__ src,
                                                   BF* __restrict__ dst, int n) {
    int i = (blockIdx.x * 256 + threadIdx.x) * 4;
    if (i >= n) return;
    float4 v = *(const float4*)&src[i];
    dst[i]     = __float2bfloat16(v.x);
    dst[i + 1] = __float2bfloat16(v.y);
    dst[i + 2] = __float2bfloat16(v.z);
    dst[i + 3] = __float2bfloat16(v.w);
}

// ---------------------------------------------------------------------------
// GroupNorm stats: one block per (b,g). A (b,g) group is a CONTIGUOUS run of
// 16 channels * 4096 spatial = 65536 fp32 elements in x ([B,C,H,W] layout).
// ---------------------------------------------------------------------------
__global__ __launch_bounds__(256) void gn_stats(const float* __restrict__ x,
                                                float* __restrict__ stats) {
    const int bg = blockIdx.x;                 // b*32+g
    const long base = (long)bg * 65536;
    float s = 0.f, q = 0.f;
    for (int i = threadIdx.x * 4; i < 65536; i += 256 * 4) {
        float4 v4 = *(const float4*)&x[base + i];
        s += v4.x + v4.y + v4.z + v4.w;
        q += v4.x * v4.x + v4.y * v4.y + v4.z * v4.z + v4.w * v4.w;
    }
#pragma unroll
    for (int o = 32; o; o >>= 1) { s += __shfl_down(s, o); q += __shfl_down(q, o); }
    __shared__ float rs[4], rq[4];
    const int w = threadIdx.x >> 6;
    if ((threadIdx.x & 63) == 0) { rs[w] = s; rq[w] = q; }
    __syncthreads();
    if (threadIdx.x == 0) {
        s = rs[0] + rs[1] + rs[2] + rs[3];
        q = rq[0] + rq[1] + rq[2] + rq[3];
        float mean = s * (1.f / 65536.f);
        float var = q * (1.f / 65536.f) - mean * mean;
        stats[2 * bg]     = mean;
        stats[2 * bg + 1] = rsqrtf(fmaxf(var, 0.f) + 1e-6f);
    }
}

// ---------------------------------------------------------------------------
// GroupNorm apply + transpose [B,C,HW] (fp32) -> n [B,HW,C] (bf16).
// 64x64 LDS tiles; grid (HW/64, C/64, B), block 256.
// ---------------------------------------------------------------------------
__global__ __launch_bounds__(256) void gn_apply(const float* __restrict__ x,
                                                const float* __restrict__ gamma,
                                                const float* __restrict__ beta,
                                                const float* __restrict__ stats,
                                                BF* __restrict__ n) {
    __shared__ float tile[64][65];
    const int b = blockIdx.z, c0 = blockIdx.y * 64, s0 = blockIdx.x * 64;
    const long xbase = ((long)b * NC + c0) * NHW + s0;
#pragma unroll
    for (int i = 0; i < 16; i++) {
        int lin = i * 256 + threadIdx.x;
        int cl = lin >> 6, sl = lin & 63;
        int c = c0 + cl;
        float2 mr = ((const float2*)stats)[b * NG + (c >> 4)];
        float v = x[xbase + (long)cl * NHW + sl];
        v = (v - mr.x) * mr.y * gamma[c] + beta[c];
        tile[cl][sl] = v;
    }
    __syncthreads();
    const long nbase = ((long)b * NHW + s0) * NC + c0;
#pragma unroll
    for (int i = 0; i < 16; i++) {
        int lin = i * 256 + threadIdx.x;
        int sl = lin >> 6, cl = lin & 63;
        n[nbase + (long)sl * NC + cl] = __float2bfloat16(tile[cl][sl]);
    }
}

// ---------------------------------------------------------------------------
// GEMM: C[m][n] = scale * sum_k A[m][k]*B[n][k]  (+ bias[n])
// A: [M,K] row-major bf16 (K-contig), B: [N,K] row-major bf16 (K-contig).
// Tile 128x128, BK=32, 4 waves each computing 64x64 (4x4 of 16x16x32 MFMA).
// LDS rows padded to 40 elems (80B) -> <=2-way bank aliasing (free).
// TRANS=1 stores C[n][m] (used to produce v transposed). Output bf16.
// ---------------------------------------------------------------------------
#define PK 40
template <bool BIAS, bool TRANS>
__global__ __launch_bounds__(256, 2) void gemm_bt(
    const BF* __restrict__ A, long aStride,
    const BF* __restrict__ Bm, long bStride,
    BF* __restrict__ C, long cStride,
    const float* __restrict__ bias,
    int M, int N, int K, float scale)
{
    __shared__ BF sA[128 * PK];
    __shared__ BF sB[128 * PK];
    const int tid = threadIdx.x;
    const int wave = tid >> 6, lane = tid & 63;
    const int bm = blockIdx.y * 128, bn = blockIdx.x * 128;
    const BF* Ab = A + (long)blockIdx.z * aStride + (long)bm * K;
    const BF* Bb = Bm + (long)blockIdx.z * bStride + (long)bn * K;

    // staging: thread t covers rows (t>>2) and (t>>2)+64, k-chunk (t&3)*8
    const int srow = tid >> 2, sko = (tid & 3) * 8;
    const BF* ga = Ab + (long)srow * K + sko;
    const BF* gb = Bb + (long)srow * K + sko;
    BF* la = &sA[srow * PK + sko];
    BF* lb = &sB[srow * PK + sko];
    const long rs64 = (long)64 * K;

    int4 a0 = *(const int4*)(ga);
    int4 a1 = *(const int4*)(ga + rs64);
    int4 b0 = *(const int4*)(gb);
    int4 b1 = *(const int4*)(gb + rs64);

    floatx4 acc[4][4];
#pragma unroll
    for (int i = 0; i < 4; i++)
#pragma unroll
        for (int j = 0; j < 4; j++)
            acc[i][j] = (floatx4){0.f, 0.f, 0.f, 0.f};

    const int wm = (wave >> 1) * 64, wn = (wave & 1) * 64;
    const int lr = lane & 15, lk = (lane >> 4) * 8;

    for (int k0 = 0; k0 < K; k0 += 32) {
        __syncthreads();   // previous compute done -> LDS free
        *(int4*)la = a0;  *(int4*)(la + 64 * PK) = a1;
        *(int4*)lb = b0;  *(int4*)(lb + 64 * PK) = b1;
        __syncthreads();   // tile visible
        if (k0 + 32 < K) { // prefetch next K-tile while MFMAs run
            ga += 32; gb += 32;
            a0 = *(const int4*)(ga); a1 = *(const int4*)(ga + rs64);
            b0 = *(const int4*)(gb); b1 = *(const int4*)(gb + rs64);
        }
        bhalf8 af[4], bfr[4];
#pragma unroll
        for (int i = 0; i < 4; i++)
            af[i] = *(const bhalf8*)&sA[(wm + i * 16 + lr) * PK + lk];
#pragma unroll
        for (int i = 0; i < 4; i++)
            bfr[i] = *(const bhalf8*)&sB[(wn + i * 16 + lr) * PK + lk];
#pragma unroll
        for (int mi = 0; mi < 4; mi++)
#pragma unroll
            for (int ni = 0; ni < 4; ni++)
                acc[mi][ni] = __builtin_amdgcn_mfma_f32_16x16x32_bf16(
                    af[mi], bfr[ni], acc[mi][ni], 0, 0, 0);
    }

    // epilogue: C/D layout col=lane&15, row=(lane>>4)*4+reg
    BF* Cb = C + (long)blockIdx.z * cStride;
#pragma unroll
    for (int ni = 0; ni < 4; ni++) {
        const int col = bn + wn + ni * 16 + lr;
        const float bv = BIAS ? bias[col] : 0.0f;
#pragma unroll
        for (int mi = 0; mi < 4; mi++) {
            const int row0 = bm + wm + mi * 16 + (lane >> 4) * 4;
#pragma unroll
            for (int r = 0; r < 4; r++) {
                float v = acc[mi][ni][r] * scale + bv;
                if (TRANS) Cb[(long)col * M + row0 + r] = __float2bfloat16(v);
                else       Cb[(long)(row0 + r) * N + col] = __float2bfloat16(v);
            }
        }
    }
}

// ---------------------------------------------------------------------------
// Row softmax over 4096 cols, in place on bf16 S. One block per row.
// ---------------------------------------------------------------------------
__global__ __launch_bounds__(256) void softmax4096(BF* __restrict__ S) {
    const long base = (long)blockIdx.x * 4096 + threadIdx.x * 16;
    const int tid = threadIdx.x, w = tid >> 6;
    bhalf8 u = *(bhalf8*)&S[base];
    bhalf8 u2 = *(bhalf8*)&S[base + 8];
    float v[16];
    float m = -1e30f;
#pragma unroll
    for (int j = 0; j < 8; j++) { v[j] = b2f(u[j]); v[8 + j] = b2f(u2[j]); }
#pragma unroll
    for (int j = 0; j < 16; j++) m = fmaxf(m, v[j]);
#pragma unroll
    for (int o = 32; o; o >>= 1) m = fmaxf(m, __shfl_xor(m, o));
    __shared__ float rm[4], rs[4];
    if ((tid & 63) == 0) rm[w] = m;
    __syncthreads();
    m = fmaxf(fmaxf(rm[0], rm[1]), fmaxf(rm[2], rm[3]));
    float s = 0.f;
#pragma unroll
    for (int j = 0; j < 16; j++) { v[j] = __expf(v[j] - m); s += v[j]; }
#pragma unroll
    for (int o = 32; o; o >>= 1) s += __shfl_xor(s, o);
    if ((tid & 63) == 0) rs[w] = s;
    __syncthreads();
    s = rs[0] + rs[1] + rs[2] + rs[3];
    const float inv = 1.0f / s;
#pragma unroll
    for (int j = 0; j < 8; j++) { u[j] = f2b(v[j] * inv); u2[j] = f2b(v[8 + j] * inv); }
    *(bhalf8*)&S[base] = u;
    *(bhalf8*)&S[base + 8] = u2;
}

// ---------------------------------------------------------------------------
// fin [B,HW,C] (bf16) -> transpose to [B,C,HW], add residual x (fp32),
// write d_out (fp32).
// ---------------------------------------------------------------------------
__global__ __launch_bounds__(256) void add_residual_T(const BF* __restrict__ fin,
                                                      const float* __restrict__ x,
                                                      float* __restrict__ out) {
    __shared__ float tile[64][65];
    const int b = blockIdx.z, c0 = blockIdx.y * 64, s0 = blockIdx.x * 64;
    const long fbase = ((long)b * NHW + s0) * NC + c0;
#pragma unroll
    for (int i = 0; i < 16; i++) {
        int lin = i * 256 + threadIdx.x;
        int sl = lin >> 6, cl = lin & 63;
        tile[sl][cl] = __bfloat162float(fin[fbase + (long)sl * NC + cl]);
    }
    __syncthreads();
    const long obase = ((long)b * NC + c0) * NHW + s0;
#pragma unroll
    for (int i = 0; i < 16; i++) {
        int lin = i * 256 + threadIdx.x;
        int cl = lin >> 6, sl = lin & 63;
        long a = obase + (long)cl * NHW + sl;
        out[a] = tile[sl][cl] + x[a];
    }
}

// ---------------------------------------------------------------------------
extern "C" void kernel_launch(void* const* d_in, const int* in_sizes, int n_in,
                              void* d_out, int out_size, void* d_ws, size_t ws_size,
                              hipStream_t stream) {
    const float* x     = (const float*)d_in[0];
    const float* gamma = (const float*)d_in[1];
    const float* beta  = (const float*)d_in[2];
    const float* Wq    = (const float*)d_in[3];
    const float* bq    = (const float*)d_in[4];
    const float* Wk    = (const float*)d_in[5];
    const float* bk    = (const float*)d_in[6];
    const float* Wv    = (const float*)d_in[7];
    const float* bv    = (const float*)d_in[8];
    const float* Wo    = (const float*)d_in[9];
    float* out = (float*)d_out;

    const long ACTB = (long)NHW * NC;        // per-batch activation elems (2M)
    const long ACT  = (long)NB * ACTB;       // all batches (16.7M)
    const long SB   = (long)NHW * NHW;       // per-batch score elems (16.7M)
    const long WSZ  = (long)NC * NC;         // weight elems (256K)

    char* ws = (char*)d_ws;
    float* stats = (float*)ws;               // 1 KB used, pad to 4 KB
    BF* wb = (BF*)(ws + 4096);               // 4 weights bf16: 2 MB
    BF* n  = wb + 4 * WSZ;                   // [B,HW,C]; later reused as fin
    BF* q  = n + ACT;                        // [B,HW,C]; later reused as attn
    BF* kk = q + ACT;                        // [B,HW,C]
    BF* vT = kk + ACT;                       // [B,C,HW] (transposed V)
    BF* S  = vT + ACT;                       // scores: chunk batches at a time

    const size_t base_need = 4096ull + (size_t)4 * WSZ * 2 + (size_t)4 * ACT * 2;
    const size_t need_full = base_need + (size_t)NB * SB * 2;
    const int chunk = (ws_size >= need_full) ? NB : 1;   // deterministic per-session

    // weights fp32 -> bf16 (layout unchanged: [N,K] K-contig)
    f2b_convert<<<(int)(4 * WSZ / 4 + 255) / 256, 256, 0, stream>>>(Wq, wb + 0 * WSZ, (int)WSZ);
    f2b_convert<<<(int)(WSZ / 4 + 255) / 256, 256, 0, stream>>>(Wk, wb + 1 * WSZ, (int)WSZ);
    f2b_convert<<<(int)(WSZ / 4 + 255) / 256, 256, 0, stream>>>(Wv, wb + 2 * WSZ, (int)WSZ);
    f2b_convert<<<(int)(WSZ / 4 + 255) / 256, 256, 0, stream>>>(Wo, wb + 3 * WSZ, (int)WSZ);

    gn_stats<<<NB * NG, 256, 0, stream>>>(x, stats);
    gn_apply<<<dim3(NHW / 64, NC / 64, NB), 256, 0, stream>>>(x, gamma, beta, stats, n);

    // Q, K: [B,HW,C]; V: transposed [B,C,HW]
    gemm_bt<true, false><<<dim3(NC / 128, NHW / 128, NB), 256, 0, stream>>>(
        n, ACTB, wb + 0 * WSZ, 0, q, ACTB, bq, NHW, NC, NC, 1.0f);
    gemm_bt<true, false><<<dim3(NC / 128, NHW / 128, NB), 256, 0, stream>>>(
        n, ACTB, wb + 1 * WSZ, 0, kk, ACTB, bk, NHW, NC, NC, 1.0f);
    gemm_bt<true, true><<<dim3(NC / 128, NHW / 128, NB), 256, 0, stream>>>(
        n, ACTB, wb + 2 * WSZ, 0, vT, ACTB, bv, NHW, NC, NC, 1.0f);

    const float iscl = 0.044194173824159216f;  // 1/sqrt(512)
    for (int b0 = 0; b0 < NB; b0 += chunk) {
        // S = Q K^T / sqrt(C)
        gemm_bt<false, false><<<dim3(NHW / 128, NHW / 128, chunk), 256, 0, stream>>>(
            q + b0 * ACTB, ACTB, kk + b0 * ACTB, ACTB, S, SB, nullptr,
            NHW, NHW, NC, iscl);
        softmax4096<<<NHW * chunk, 256, 0, stream>>>(S);
        // attn = P V  (B operand = vT [C, HW], K-dim = j over 4096)
        gemm_bt<false, false><<<dim3(NC / 128, NHW / 128, chunk), 256, 0, stream>>>(
            S, SB, vT + b0 * ACTB, ACTB, q + b0 * ACTB, ACTB, nullptr,
            NHW, NC, NHW, 1.0f);
    }

    // fin = attn @ Wo^T  (attn lives in q buffer; fin reuses n buffer)
    gemm_bt<false, false><<<dim3(NC / 128, NHW / 128, NB), 256, 0, stream>>>(
        q, ACTB, wb + 3 * WSZ, 0, n, ACTB, nullptr, NHW, NC, NC, 1.0f);

    // out = fin^T + x
    add_residual_T<<<dim3(NHW / 64, NC / 64, NB), 256, 0, stream>>>(n, x, out);
}

// Round 3
// 889.526 us; speedup vs baseline: 1.2878x; 1.2878x over previous
//
#include <hip/hip_runtime.h>
#include <hip/hip_bf16.h>
#include <cstdint>
#include <cstddef>

typedef __hip_bfloat16 BF;
typedef __attribute__((ext_vector_type(8))) short bhalf8;   // 8 bf16 (MFMA A/B frag)
typedef __attribute__((ext_vector_type(4))) float floatx4;  // MFMA C/D frag

#define NB 8
#define NC 512
#define NHW 4096
#define NG 32

__device__ __forceinline__ float b2f(short h) {
    union { unsigned u; float f; } c;
    c.u = ((unsigned)(unsigned short)h) << 16;
    return c.f;
}
__device__ __forceinline__ short f2b(float f) {
    __hip_bfloat16 h = __float2bfloat16(f);
    short s;
    __builtin_memcpy(&s, &h, 2);
    return s;
}

// 16B global -> LDS direct (wave-uniform LDS base + lane*16)
__device__ __forceinline__ void gload16(const BF* g, BF* l) {
    __builtin_amdgcn_global_load_lds(
        (const __attribute__((address_space(1))) void*)g,
        (__attribute__((address_space(3))) void*)l, 16, 0, 0);
}

// ---------------------------------------------------------------------------
__global__ __launch_bounds__(256) void f2b_convert(const float* __restrict__ src,
                                                   BF* __restrict__ dst, int n) {
    int i = (blockIdx.x * 256 + threadIdx.x) * 4;
    if (i >= n) return;
    float4 v = *(const float4*)&src[i];
    dst[i]     = __float2bfloat16(v.x);
    dst[i + 1] = __float2bfloat16(v.y);
    dst[i + 2] = __float2bfloat16(v.z);
    dst[i + 3] = __float2bfloat16(v.w);
}

// ---------------------------------------------------------------------------
__global__ __launch_bounds__(256) void gn_stats(const float* __restrict__ x,
                                                float* __restrict__ stats) {
    const int bg = blockIdx.x;
    const long base = (long)bg * 65536;
    float s = 0.f, q = 0.f;
    for (int i = threadIdx.x * 4; i < 65536; i += 256 * 4) {
        float4 v4 = *(const float4*)&x[base + i];
        s += v4.x + v4.y + v4.z + v4.w;
        q += v4.x * v4.x + v4.y * v4.y + v4.z * v4.z + v4.w * v4.w;
    }
#pragma unroll
    for (int o = 32; o; o >>= 1) { s += __shfl_down(s, o); q += __shfl_down(q, o); }
    __shared__ float rs[4], rq[4];
    const int w = threadIdx.x >> 6;
    if ((threadIdx.x & 63) == 0) { rs[w] = s; rq[w] = q; }
    __syncthreads();
    if (threadIdx.x == 0) {
        s = rs[0] + rs[1] + rs[2] + rs[3];
        q = rq[0] + rq[1] + rq[2] + rq[3];
        float mean = s * (1.f / 65536.f);
        float var = q * (1.f / 65536.f) - mean * mean;
        stats[2 * bg]     = mean;
        stats[2 * bg + 1] = rsqrtf(fmaxf(var, 0.f) + 1e-6f);
    }
}

// ---------------------------------------------------------------------------
__global__ __launch_bounds__(256) void gn_apply(const float* __restrict__ x,
                                                const float* __restrict__ gamma,
                                                const float* __restrict__ beta,
                                                const float* __restrict__ stats,
                                                BF* __restrict__ n) {
    __shared__ float tile[64][65];
    const int b = blockIdx.z, c0 = blockIdx.y * 64, s0 = blockIdx.x * 64;
    const long xbase = ((long)b * NC + c0) * NHW + s0;
#pragma unroll
    for (int i = 0; i < 16; i++) {
        int lin = i * 256 + threadIdx.x;
        int cl = lin >> 6, sl = lin & 63;
        int c = c0 + cl;
        float2 mr = ((const float2*)stats)[b * NG + (c >> 4)];
        float v = x[xbase + (long)cl * NHW + sl];
        v = (v - mr.x) * mr.y * gamma[c] + beta[c];
        tile[cl][sl] = v;
    }
    __syncthreads();
    const long nbase = ((long)b * NHW + s0) * NC + c0;
#pragma unroll
    for (int i = 0; i < 16; i++) {
        int lin = i * 256 + threadIdx.x;
        int sl = lin >> 6, cl = lin & 63;
        n[nbase + (long)sl * NC + cl] = __float2bfloat16(tile[cl][sl]);
    }
}

// ---------------------------------------------------------------------------
// GEMM 128x128 tile, BK=32: C[m][n] = scale*sum_k A[m][k]*B[n][k] (+bias[n])
// A [M,K], B [N,K] both K-contig bf16. m97-style global_load_lds staging
// (unpadded 128x32 LDS tiles). 4 waves, each 64x64 (4x4 MFMA 16x16x32).
// ---------------------------------------------------------------------------
template <bool BIAS, bool TRANS>
__global__ __launch_bounds__(256, 2) void gemm128(
    const BF* __restrict__ A, long aStride,
    const BF* __restrict__ Bm, long bStride,
    BF* __restrict__ C, long cStride,
    const float* __restrict__ bias,
    int M, int N, int K, float scale)
{
    __shared__ __align__(16) BF sA[128 * 32];
    __shared__ __align__(16) BF sB[128 * 32];
    const int tid = threadIdx.x;
    const int wave = tid >> 6, lane = tid & 63;
    const int bm = blockIdx.y * 128, bn = blockIdx.x * 128;
    const BF* Ab = A + (long)blockIdx.z * aStride + (long)bm * K;
    const BF* Bb = Bm + (long)blockIdx.z * bStride + (long)bn * K;

    // staging: wave w covers rows [w*32, w*32+32), 2 instrs of 16 rows each.
    // lane l -> row_off l>>2, 16B chunk l&3 (row = 32 elems = 4 chunks).
    const int srow = wave * 32 + (lane >> 2);
    const int sk = (lane & 3) * 8;
    const BF* gA0 = Ab + (long)srow * K + sk;
    const BF* gA1 = gA0 + (long)16 * K;
    const BF* gB0 = Bb + (long)srow * K + sk;
    const BF* gB1 = gB0 + (long)16 * K;
    BF* lA0 = &sA[(wave * 32) * 32];
    BF* lA1 = &sA[(wave * 32 + 16) * 32];
    BF* lB0 = &sB[(wave * 32) * 32];
    BF* lB1 = &sB[(wave * 32 + 16) * 32];

    floatx4 acc[4][4];
#pragma unroll
    for (int i = 0; i < 4; i++)
#pragma unroll
        for (int j = 0; j < 4; j++) acc[i][j] = (floatx4){0.f, 0.f, 0.f, 0.f};

    const int wm = (wave >> 1) * 64, wn = (wave & 1) * 64;
    const int lr = lane & 15, lk = (lane >> 4) * 8;

    for (int k0 = 0; k0 < K; k0 += 32) {
        __syncthreads();               // prev tile consumed
        gload16(gA0 + k0, lA0);
        gload16(gA1 + k0, lA1);
        gload16(gB0 + k0, lB0);
        gload16(gB1 + k0, lB1);
        __syncthreads();               // drains vmcnt -> tile visible
        bhalf8 af[4], bfr[4];
#pragma unroll
        for (int i = 0; i < 4; i++)
            af[i] = *(const bhalf8*)&sA[(wm + i * 16 + lr) * 32 + lk];
#pragma unroll
        for (int i = 0; i < 4; i++)
            bfr[i] = *(const bhalf8*)&sB[(wn + i * 16 + lr) * 32 + lk];
#pragma unroll
        for (int mi = 0; mi < 4; mi++)
#pragma unroll
            for (int ni = 0; ni < 4; ni++)
                acc[mi][ni] = __builtin_amdgcn_mfma_f32_16x16x32_bf16(
                    af[mi], bfr[ni], acc[mi][ni], 0, 0, 0);
    }

    BF* Cb = C + (long)blockIdx.z * cStride;
#pragma unroll
    for (int ni = 0; ni < 4; ni++) {
        const int col = bn + wn + ni * 16 + lr;
        const float bv = BIAS ? bias[col] : 0.0f;
#pragma unroll
        for (int mi = 0; mi < 4; mi++) {
            const int row0 = bm + wm + mi * 16 + (lane >> 4) * 4;
#pragma unroll
            for (int r = 0; r < 4; r++) {
                float v = acc[mi][ni][r] * scale + bv;
                if (TRANS) Cb[(long)col * M + row0 + r] = __float2bfloat16(v);
                else       Cb[(long)(row0 + r) * N + col] = __float2bfloat16(v);
            }
        }
    }
}

// ---------------------------------------------------------------------------
// GEMM 64(M)x128(N) tile, BK=32 — for grid-starved shapes (PV at small chunk).
// 4 waves in 2x2, each 32x64 (2x4 MFMA).
// ---------------------------------------------------------------------------
__global__ __launch_bounds__(256, 2) void gemm64(
    const BF* __restrict__ A, long aStride,
    const BF* __restrict__ Bm, long bStride,
    BF* __restrict__ C, long cStride,
    int N, int K, float scale)
{
    __shared__ __align__(16) BF sA[64 * 32];
    __shared__ __align__(16) BF sB[128 * 32];
    const int tid = threadIdx.x;
    const int wave = tid >> 6, lane = tid & 63;
    const int bm = blockIdx.y * 64, bn = blockIdx.x * 128;
    const BF* Ab = A + (long)blockIdx.z * aStride + (long)bm * K;
    const BF* Bb = Bm + (long)blockIdx.z * bStride + (long)bn * K;

    const int rowoff = lane >> 2, sk = (lane & 3) * 8;
    const BF* gA0 = Ab + (long)(wave * 16 + rowoff) * K + sk;      // 1 instr: 16 rows
    const BF* gB0 = Bb + (long)(wave * 32 + rowoff) * K + sk;      // 2 instrs
    const BF* gB1 = gB0 + (long)16 * K;
    BF* lA0 = &sA[(wave * 16) * 32];
    BF* lB0 = &sB[(wave * 32) * 32];
    BF* lB1 = &sB[(wave * 32 + 16) * 32];

    floatx4 acc[2][4];
#pragma unroll
    for (int i = 0; i < 2; i++)
#pragma unroll
        for (int j = 0; j < 4; j++) acc[i][j] = (floatx4){0.f, 0.f, 0.f, 0.f};

    const int wm = (wave >> 1) * 32, wn = (wave & 1) * 64;
    const int lr = lane & 15, lk = (lane >> 4) * 8;

    for (int k0 = 0; k0 < K; k0 += 32) {
        __syncthreads();
        gload16(gA0 + k0, lA0);
        gload16(gB0 + k0, lB0);
        gload16(gB1 + k0, lB1);
        __syncthreads();
        bhalf8 af[2], bfr[4];
#pragma unroll
        for (int i = 0; i < 2; i++)
            af[i] = *(const bhalf8*)&sA[(wm + i * 16 + lr) * 32 + lk];
#pragma unroll
        for (int i = 0; i < 4; i++)
            bfr[i] = *(const bhalf8*)&sB[(wn + i * 16 + lr) * 32 + lk];
#pragma unroll
        for (int mi = 0; mi < 2; mi++)
#pragma unroll
            for (int ni = 0; ni < 4; ni++)
                acc[mi][ni] = __builtin_amdgcn_mfma_f32_16x16x32_bf16(
                    af[mi], bfr[ni], acc[mi][ni], 0, 0, 0);
    }

    BF* Cb = C + (long)blockIdx.z * cStride;
#pragma unroll
    for (int ni = 0; ni < 4; ni++) {
        const int col = bn + wn + ni * 16 + lr;
#pragma unroll
        for (int mi = 0; mi < 2; mi++) {
            const int row0 = bm + wm + mi * 16 + (lane >> 4) * 4;
#pragma unroll
            for (int r = 0; r < 4; r++)
                Cb[(long)(row0 + r) * N + col] = __float2bfloat16(acc[mi][ni][r] * scale);
        }
    }
}

// ---------------------------------------------------------------------------
__global__ __launch_bounds__(256) void softmax4096(BF* __restrict__ S) {
    const long base = (long)blockIdx.x * 4096 + threadIdx.x * 16;
    const int tid = threadIdx.x, w = tid >> 6;
    bhalf8 u = *(bhalf8*)&S[base];
    bhalf8 u2 = *(bhalf8*)&S[base + 8];
    float v[16];
    float m = -1e30f;
#pragma unroll
    for (int j = 0; j < 8; j++) { v[j] = b2f(u[j]); v[8 + j] = b2f(u2[j]); }
#pragma unroll
    for (int j = 0; j < 16; j++) m = fmaxf(m, v[j]);
#pragma unroll
    for (int o = 32; o; o >>= 1) m = fmaxf(m, __shfl_xor(m, o));
    __shared__ float rm[4], rs[4];
    if ((tid & 63) == 0) rm[w] = m;
    __syncthreads();
    m = fmaxf(fmaxf(rm[0], rm[1]), fmaxf(rm[2], rm[3]));
    float s = 0.f;
#pragma unroll
    for (int j = 0; j < 16; j++) { v[j] = __expf(v[j] - m); s += v[j]; }
#pragma unroll
    for (int o = 32; o; o >>= 1) s += __shfl_xor(s, o);
    if ((tid & 63) == 0) rs[w] = s;
    __syncthreads();
    s = rs[0] + rs[1] + rs[2] + rs[3];
    const float inv = 1.0f / s;
#pragma unroll
    for (int j = 0; j < 8; j++) { u[j] = f2b(v[j] * inv); u2[j] = f2b(v[8 + j] * inv); }
    *(bhalf8*)&S[base] = u;
    *(bhalf8*)&S[base + 8] = u2;
}

// ---------------------------------------------------------------------------
__global__ __launch_bounds__(256) void add_residual_T(const BF* __restrict__ fin,
                                                      const float* __restrict__ x,
                                                      float* __restrict__ out) {
    __shared__ float tile[64][65];
    const int b = blockIdx.z, c0 = blockIdx.y * 64, s0 = blockIdx.x * 64;
    const long fbase = ((long)b * NHW + s0) * NC + c0;
#pragma unroll
    for (int i = 0; i < 16; i++) {
        int lin = i * 256 + threadIdx.x;
        int sl = lin >> 6, cl = lin & 63;
        tile[sl][cl] = __bfloat162float(fin[fbase + (long)sl * NC + cl]);
    }
    __syncthreads();
    const long obase = ((long)b * NC + c0) * NHW + s0;
#pragma unroll
    for (int i = 0; i < 16; i++) {
        int lin = i * 256 + threadIdx.x;
        int cl = lin >> 6, sl = lin & 63;
        long a = obase + (long)cl * NHW + sl;
        out[a] = tile[sl][cl] + x[a];
    }
}

// ---------------------------------------------------------------------------
extern "C" void kernel_launch(void* const* d_in, const int* in_sizes, int n_in,
                              void* d_out, int out_size, void* d_ws, size_t ws_size,
                              hipStream_t stream) {
    const float* x     = (const float*)d_in[0];
    const float* gamma = (const float*)d_in[1];
    const float* beta  = (const float*)d_in[2];
    const float* Wq    = (const float*)d_in[3];
    const float* bq    = (const float*)d_in[4];
    const float* Wk    = (const float*)d_in[5];
    const float* bk    = (const float*)d_in[6];
    const float* Wv    = (const float*)d_in[7];
    const float* bv    = (const float*)d_in[8];
    const float* Wo    = (const float*)d_in[9];
    float* out = (float*)d_out;

    const long ACTB = (long)NHW * NC;        // 2M elems / batch
    const long SB   = (long)NHW * NHW;       // 16.7M elems / batch
    const long WSZ  = (long)NC * NC;

    // layout: stats | wb | q | kk | vT | R (n, then S, then fin — disjoint lifetimes)
    char* ws = (char*)d_ws;
    float* stats = (float*)ws;
    BF* wb = (BF*)(ws + 4096);
    BF* q  = wb + 4 * WSZ;
    BF* kk = q + NB * ACTB;
    BF* vT = kk + NB * ACTB;
    BF* R  = vT + NB * ACTB;
    BF* n = R;   // live: GN -> QKV GEMMs
    BF* S = R;   // live: attention chunks
    BF* fin = R; // live: Wo GEMM -> residual

    const size_t base_need = 4096ull + (size_t)4 * WSZ * 2 + (size_t)3 * NB * ACTB * 2;
    long sroom = (ws_size > base_need) ? (long)((ws_size - base_need) / (SB * 2)) : 1;
    int chunk = (int)(sroom < 1 ? 1 : (sroom > NB ? NB : sroom));
    while (NB % chunk) chunk--;              // 8,4,2,1

    f2b_convert<<<256, 256, 0, stream>>>(Wq, wb + 0 * WSZ, (int)WSZ);
    f2b_convert<<<256, 256, 0, stream>>>(Wk, wb + 1 * WSZ, (int)WSZ);
    f2b_convert<<<256, 256, 0, stream>>>(Wv, wb + 2 * WSZ, (int)WSZ);
    f2b_convert<<<256, 256, 0, stream>>>(Wo, wb + 3 * WSZ, (int)WSZ);

    gn_stats<<<NB * NG, 256, 0, stream>>>(x, stats);
    gn_apply<<<dim3(NHW / 64, NC / 64, NB), 256, 0, stream>>>(x, gamma, beta, stats, n);

    gemm128<true, false><<<dim3(NC / 128, NHW / 128, NB), 256, 0, stream>>>(
        n, ACTB, wb + 0 * WSZ, 0, q, ACTB, bq, NHW, NC, NC, 1.0f);
    gemm128<true, false><<<dim3(NC / 128, NHW / 128, NB), 256, 0, stream>>>(
        n, ACTB, wb + 1 * WSZ, 0, kk, ACTB, bk, NHW, NC, NC, 1.0f);
    gemm128<true, true><<<dim3(NC / 128, NHW / 128, NB), 256, 0, stream>>>(
        n, ACTB, wb + 2 * WSZ, 0, vT, ACTB, bv, NHW, NC, NC, 1.0f);

    const float iscl = 0.044194173824159216f;  // 1/sqrt(512)
    for (int b0 = 0; b0 < NB; b0 += chunk) {
        gemm128<false, false><<<dim3(NHW / 128, NHW / 128, chunk), 256, 0, stream>>>(
            q + b0 * ACTB, ACTB, kk + b0 * ACTB, ACTB, S, SB, nullptr,
            NHW, NHW, NC, iscl);
        softmax4096<<<NHW * chunk, 256, 0, stream>>>(S);
        if (chunk >= 4)
            gemm128<false, false><<<dim3(NC / 128, NHW / 128, chunk), 256, 0, stream>>>(
                S, SB, vT + b0 * ACTB, ACTB, q + b0 * ACTB, ACTB, nullptr,
                NHW, NC, NHW, 1.0f);
        else
            gemm64<<<dim3(NC / 128, NHW / 64, chunk), 256, 0, stream>>>(
                S, SB, vT + b0 * ACTB, ACTB, q + b0 * ACTB, ACTB, NC, NHW, 1.0f);
    }

    gemm128<false, false><<<dim3(NC / 128, NHW / 128, NB), 256, 0, stream>>>(
        q, ACTB, wb + 3 * WSZ, 0, fin, ACTB, nullptr, NHW, NC, NC, 1.0f);

    add_residual_T<<<dim3(NHW / 64, NC / 64, NB), 256, 0, stream>>>(fin, x, out);
}